// Round 1
// baseline (36.130 us; speedup 1.0000x reference)
//
#include <hip/hip_runtime.h>

#define B_   16
#define NC_  1024
#define NQ_  128
#define D_   512

typedef __attribute__((ext_vector_type(8))) short bf16x8;
typedef __attribute__((ext_vector_type(4))) float f32x4;

// fp32 -> bf16 round-to-nearest-even (finite inputs only; no NaNs in this problem)
__device__ __forceinline__ short f2bf(float x) {
    unsigned u = __builtin_bit_cast(unsigned, x);
    u += 0x7fffu + ((u >> 16) & 1u);
    return (short)(u >> 16);
}

// Pre-kernel: qw[b][j][d] = bf16(q * w_cq); qterm[b][j] = q . w_q (fp32); wcb = bf16(w_c)
__global__ __launch_bounds__(256) void prep_kernel(
    const float* __restrict__ q, const float* __restrict__ kern,
    short* __restrict__ qw, float* __restrict__ qterm, short* __restrict__ wcb)
{
    const int tid  = threadIdx.x;
    const int lane = tid & 63;
    const int row  = blockIdx.x * 4 + (tid >> 6);   // 0..2047 (b*128 + j)
    const int k0   = lane * 8;
    const float* qr = q + (size_t)row * D_;
    f32x4 a0 = *(const f32x4*)(qr + k0);
    f32x4 a1 = *(const f32x4*)(qr + k0 + 4);
    f32x4 c0 = *(const f32x4*)(kern + 2 * D_ + k0);      // w_cq
    f32x4 c1 = *(const f32x4*)(kern + 2 * D_ + k0 + 4);
    f32x4 w0 = *(const f32x4*)(kern + D_ + k0);          // w_q
    f32x4 w1 = *(const f32x4*)(kern + D_ + k0 + 4);
    bf16x8 o;
    o[0] = f2bf(a0[0] * c0[0]); o[1] = f2bf(a0[1] * c0[1]);
    o[2] = f2bf(a0[2] * c0[2]); o[3] = f2bf(a0[3] * c0[3]);
    o[4] = f2bf(a1[0] * c1[0]); o[5] = f2bf(a1[1] * c1[1]);
    o[6] = f2bf(a1[2] * c1[2]); o[7] = f2bf(a1[3] * c1[3]);
    *(bf16x8*)(qw + (size_t)row * D_ + k0) = o;
    float s = a0[0]*w0[0] + a0[1]*w0[1] + a0[2]*w0[2] + a0[3]*w0[3]
            + a1[0]*w1[0] + a1[1]*w1[1] + a1[2]*w1[2] + a1[3]*w1[3];
    s += __shfl_xor(s, 1);  s += __shfl_xor(s, 2);  s += __shfl_xor(s, 4);
    s += __shfl_xor(s, 8);  s += __shfl_xor(s, 16); s += __shfl_xor(s, 32);
    if (lane == 0) qterm[row] = s;
    if (blockIdx.x == 0) {          // w_c -> bf16, once
        wcb[tid]       = f2bf(kern[tid]);
        wcb[tid + 256] = f2bf(kern[tid + 256]);
    }
}

// Main: out[b][i][j] = (c[b][i] . qw[b][j]) + cterm[b][i] + qterm[b][j] + bias
// Block: 64.. no — 32 rows x 128 cols; 4 waves as 2(M) x 2(N); wave tile 16x64.
// No LDS staging; A fp32->bf16 in regs; cterm via extra MFMA with B = w_c broadcast.
__global__ __launch_bounds__(256) void sim_kernel(
    const float* __restrict__ c, const short* __restrict__ qw,
    const float* __restrict__ qterm, const short* __restrict__ wcb,
    const float* __restrict__ bias_p, float* __restrict__ out)
{
    const int bid  = blockIdx.x;
    const int b    = bid >> 5;          // 32 M-tiles per batch
    const int mt   = bid & 31;
    const int tid  = threadIdx.x;
    const int lane = tid & 63;
    const int wm   = (tid >> 7) & 1;    // wave row
    const int wn   = (tid >> 6) & 1;    // wave col
    const int rif  = lane & 15;         // row/col within 16x16 frag
    const int kg   = lane >> 4;         // k-group 0..3 (8 k-elems each)

    const int rowbase = mt * 32 + wm * 16;
    const float* cA = c   + ((size_t)(b * NC_ + rowbase + rif)) * D_ + kg * 8;
    const short* qB = qw  + ((size_t)(b * NQ_ + wn * 64 + rif)) * D_ + kg * 8;
    const short* wB = wcb + kg * 8;

    f32x4 acc0 = {}, acc1 = {}, acc2 = {}, acc3 = {}, accx = {};

    #pragma unroll 4
    for (int k0 = 0; k0 < D_; k0 += 32) {
        f32x4 a0 = *(const f32x4*)(cA + k0);
        f32x4 a1 = *(const f32x4*)(cA + k0 + 4);
        bf16x8 af;
        af[0] = f2bf(a0[0]); af[1] = f2bf(a0[1]); af[2] = f2bf(a0[2]); af[3] = f2bf(a0[3]);
        af[4] = f2bf(a1[0]); af[5] = f2bf(a1[1]); af[6] = f2bf(a1[2]); af[7] = f2bf(a1[3]);
        bf16x8 b0 = *(const bf16x8*)(qB + k0);
        bf16x8 b1 = *(const bf16x8*)(qB + k0 + 16 * D_);
        bf16x8 b2 = *(const bf16x8*)(qB + k0 + 32 * D_);
        bf16x8 b3 = *(const bf16x8*)(qB + k0 + 48 * D_);
        acc0 = __builtin_amdgcn_mfma_f32_16x16x32_bf16(af, b0, acc0, 0, 0, 0);
        acc1 = __builtin_amdgcn_mfma_f32_16x16x32_bf16(af, b1, acc1, 0, 0, 0);
        acc2 = __builtin_amdgcn_mfma_f32_16x16x32_bf16(af, b2, acc2, 0, 0, 0);
        acc3 = __builtin_amdgcn_mfma_f32_16x16x32_bf16(af, b3, acc3, 0, 0, 0);
        if (wn == 0) {   // cterm: every B-column = w_c slice -> D[i][*] = cterm[i]
            bf16x8 wf = *(const bf16x8*)(wB + k0);
            accx = __builtin_amdgcn_mfma_f32_16x16x32_bf16(af, wf, accx, 0, 0, 0);
        }
    }

    __shared__ float ct[32];
    if (wn == 0 && rif == 0) {
        ct[wm * 16 + kg * 4 + 0] = accx[0];
        ct[wm * 16 + kg * 4 + 1] = accx[1];
        ct[wm * 16 + kg * 4 + 2] = accx[2];
        ct[wm * 16 + kg * 4 + 3] = accx[3];
    }
    __syncthreads();

    const float bias = *bias_p;
    const float* qt = qterm + b * NQ_ + wn * 64 + rif;
    const float qt0 = qt[0], qt1 = qt[16], qt2 = qt[32], qt3 = qt[48];
    float* o = out + ((size_t)(b * NC_ + rowbase + kg * 4)) * NQ_ + wn * 64 + rif;
    #pragma unroll
    for (int r = 0; r < 4; ++r) {
        const float base = ct[wm * 16 + kg * 4 + r] + bias;
        o[(size_t)r * NQ_ +  0] = acc0[r] + base + qt0;
        o[(size_t)r * NQ_ + 16] = acc1[r] + base + qt1;
        o[(size_t)r * NQ_ + 32] = acc2[r] + base + qt2;
        o[(size_t)r * NQ_ + 48] = acc3[r] + base + qt3;
    }
}

extern "C" void kernel_launch(void* const* d_in, const int* in_sizes, int n_in,
                              void* d_out, int out_size, void* d_ws, size_t ws_size,
                              hipStream_t stream) {
    const float* c    = (const float*)d_in[0];
    const float* q    = (const float*)d_in[1];
    const float* kern = (const float*)d_in[2];
    const float* bias = (const float*)d_in[3];
    float* out = (float*)d_out;

    // ws layout: qw bf16 [2048][512] (2 MiB) | qterm f32 [2048] | wcb bf16 [512]
    short* qw    = (short*)d_ws;
    float* qterm = (float*)((char*)d_ws + (size_t)2048 * 512 * 2);
    short* wcb   = (short*)((char*)d_ws + (size_t)2048 * 512 * 2 + 2048 * 4);

    prep_kernel<<<512, 256, 0, stream>>>(q, kern, qw, qterm, wcb);
    sim_kernel<<<512, 256, 0, stream>>>(c, qw, qterm, wcb, bias, out);
}